// Round 14
// baseline (53.824 us; speedup 1.0000x reference)
//
#include <hip/hip_runtime.h>
#include <math.h>

#define B_TOTAL 2048
#define I_DIM   128
#define O_DIM   128
#define GK      68                  // G + k rows
#define NKNOT   71
#define W_ELEMS ((size_t)GK * I_DIM * O_DIM)    // 1114112
#define WS_MIN  (W_ELEMS * 2)                   // 2.23 MB bf16 copy
#define SLICE_B (GK * O_DIM * 2)                // 17408 B per i-slice

__device__ __forceinline__ float rdlanef(float v, int sl) {
    return __int_as_float(__builtin_amdgcn_readlane(__float_as_int(v), sl));
}
__device__ __forceinline__ unsigned short f2bf(float f) {   // RNE
    unsigned u = __float_as_uint(f);
    return (unsigned short)((u + 0x7fffu + ((u >> 16) & 1u)) >> 16);
}
__device__ __forceinline__ float bflo(unsigned u) { return __uint_as_float(u << 16); }
__device__ __forceinline__ float bfhi(unsigned u) { return __uint_as_float(u & 0xffff0000u); }

// de Boor coefs (exact ref order) for one (b,i)
__device__ __forceinline__ void coef_eval(float xv, const float* t_sh,
                                          float& c0, float& c1, float& c2,
                                          float& c3, float& c4, int& g0) {
    int ik = 3 + (int)floorf((xv + 1.0f) * 32.0f);
    ik = min(max(ik, 3), 66);
    while (ik < 66 && xv >= t_sh[ik + 1]) ++ik;
    while (ik > 3 && xv < t_sh[ik]) --ik;
    float l0, l1, l2, r0, r1, r2;
    float N0 = 1.0f, N1, N2, N3;
    l0 = xv - t_sh[ik];  r0 = t_sh[ik + 1] - xv;
    { float temp = N0 / (r0 + l0); N0 = r0 * temp; N1 = l0 * temp; }
    l1 = xv - t_sh[ik - 1];  r1 = t_sh[ik + 2] - xv;
    { float saved = 0.0f, temp;
      temp = N0 / (r0 + l1); N0 = saved + r0 * temp; saved = l1 * temp;
      temp = N1 / (r1 + l0); N1 = saved + r1 * temp; N2 = l0 * temp; }
    l2 = xv - t_sh[ik - 2];  r2 = t_sh[ik + 3] - xv;
    { float saved = 0.0f, temp;
      temp = N0 / (r0 + l2); N0 = saved + r0 * temp; saved = l2 * temp;
      temp = N1 / (r1 + l1); N1 = saved + r1 * temp; saved = l1 * temp;
      temp = N2 / (r2 + l0); N2 = saved + r2 * temp; N3 = l0 * temp; }
    c0 = N0; c1 = N1; c2 = N2; c3 = N3;
    c4 = xv / (1.0f + expf(-xv));
    g0 = ik - 3;
}

// w f32 [GK][I][O] -> bf16 [I][GK][O] (transpose g<->i, o innermost).
// 1088 blocks x 256 thr. All coalesced. (R9-proven.)
__global__ __launch_bounds__(256)
void wcvt(const float* __restrict__ w, unsigned short* __restrict__ wbf) {
    const int tid = threadIdx.x;
    const int p   = blockIdx.x * 8 + (tid >> 5);    // (g,i) in source order
    const int oq  = (tid & 31) * 4;
    const int g   = p >> 7;
    const int i   = p & 127;
    const float4 v = *(const float4*)(w + (size_t)p * O_DIM + oq);
    ushort4 o4;
    o4.x = f2bf(v.x); o4.y = f2bf(v.y); o4.z = f2bf(v.z); o4.w = f2bf(v.w);
    *(ushort4*)(wbf + ((size_t)i * GK + g) * O_DIM + oq) = o4;
}

// grid = 256 blocks (1/CU), 512 thr = 8 waves; wave's b = blockIdx*8 + wave.
// Per (b,i): ONE global dwordx4 covers the whole 1KB window rows g0..g0+3
// (lane l -> row g0+(l>>4), o-range (l&15)*8), plus one broadcast dwordx4
// for the silu row, plus one ds_read_b64 for (c_q, c4/4) from a per-wave
// LDS coef table. g0 via readlane. All four quarters add identical silu
// products with c4/4 -> sums to c4*v. Epilogue: shfl_xor(16,32) reduce,
// lanes 0..15 store 32B each.
__global__ __launch_bounds__(512, 2)
void flashkan_quad(const float* __restrict__ x,
                   const unsigned short* __restrict__ wbf,
                   const float* __restrict__ t,
                   float* __restrict__ out) {
    __shared__ float t_sh[NKNOT];
    __shared__ float tab[8][I_DIM][8];      // per-wave coef table, 32 KB

    const int tid  = threadIdx.x;
    const int wave = tid >> 6;
    const int l    = tid & 63;
    const int b    = blockIdx.x * 8 + wave;
    const int q2   = (l >> 4) * 2;          // quarter -> table column pair

    if (tid < NKNOT) t_sh[tid] = t[tid];
    __syncthreads();

    // ---- coef phase: lane owns i = l and i = l + 64 ----
    float a0, a1, a2, a3, a4;  int ga;
    float e0, e1, e2, e3, e4;  int gb;
    coef_eval(x[(size_t)b * I_DIM + l],      t_sh, a0, a1, a2, a3, a4, ga);
    coef_eval(x[(size_t)b * I_DIM + l + 64], t_sh, e0, e1, e2, e3, e4, gb);

    {
        const float a4q = a4 * 0.25f, e4q = e4 * 0.25f;
        float4* tp0 = (float4*)&tab[wave][l][0];
        tp0[0] = make_float4(a0, a4q, a1, a4q);
        tp0[1] = make_float4(a2, a4q, a3, a4q);
        float4* tp1 = (float4*)&tab[wave][l + 64][0];
        tp1[0] = make_float4(e0, e4q, e1, e4q);
        tp1[1] = make_float4(e2, e4q, e3, e4q);
    }
    // table is per-wave: no barrier needed; compiler orders ds ops via lgkmcnt

    const char* wb = (const char*)wbf;
    const int spl_off  = l * 16;                    // lane's slot in 1KB window
    const int silu_off = 67 * 256 + (l & 15) * 16;  // silu row, bcast across quarters

    float acc[8];
    #pragma unroll
    for (int e = 0; e < 8; ++e) acc[e] = 0.0f;

    #pragma unroll 4
    for (int k = 0; k < 64; ++k) {
        const int g0 = __builtin_amdgcn_readlane(ga, k);
        const float2 cq = *(const float2*)&tab[wave][k][q2];    // (c_q, c4/4)
        const char* sl = wb + (size_t)k * SLICE_B;
        const uint4 u = *(const uint4*)(sl + g0 * 256 + spl_off);
        const uint4 s = *(const uint4*)(sl + silu_off);
        acc[0] += cq.x * bflo(u.x) + cq.y * bflo(s.x);
        acc[1] += cq.x * bfhi(u.x) + cq.y * bfhi(s.x);
        acc[2] += cq.x * bflo(u.y) + cq.y * bflo(s.y);
        acc[3] += cq.x * bfhi(u.y) + cq.y * bfhi(s.y);
        acc[4] += cq.x * bflo(u.z) + cq.y * bflo(s.z);
        acc[5] += cq.x * bfhi(u.z) + cq.y * bfhi(s.z);
        acc[6] += cq.x * bflo(u.w) + cq.y * bflo(s.w);
        acc[7] += cq.x * bfhi(u.w) + cq.y * bfhi(s.w);
    }
    #pragma unroll 4
    for (int k = 0; k < 64; ++k) {
        const int g0 = __builtin_amdgcn_readlane(gb, k);
        const float2 cq = *(const float2*)&tab[wave][k + 64][q2];
        const char* sl = wb + (size_t)(k + 64) * SLICE_B;
        const uint4 u = *(const uint4*)(sl + g0 * 256 + spl_off);
        const uint4 s = *(const uint4*)(sl + silu_off);
        acc[0] += cq.x * bflo(u.x) + cq.y * bflo(s.x);
        acc[1] += cq.x * bfhi(u.x) + cq.y * bfhi(s.x);
        acc[2] += cq.x * bflo(u.y) + cq.y * bflo(s.y);
        acc[3] += cq.x * bfhi(u.y) + cq.y * bfhi(s.y);
        acc[4] += cq.x * bflo(u.z) + cq.y * bflo(s.z);
        acc[5] += cq.x * bfhi(u.z) + cq.y * bfhi(s.z);
        acc[6] += cq.x * bflo(u.w) + cq.y * bflo(s.w);
        acc[7] += cq.x * bfhi(u.w) + cq.y * bfhi(s.w);
    }

    // ---- cross-quarter reduce: lanes l, l^16, l^32, l^48 share o-range ----
    #pragma unroll
    for (int e = 0; e < 8; ++e) acc[e] += __shfl_xor(acc[e], 16);
    #pragma unroll
    for (int e = 0; e < 8; ++e) acc[e] += __shfl_xor(acc[e], 32);

    if (l < 16) {
        float* dp = out + (size_t)b * O_DIM + l * 8;
        *(float4*)dp       = make_float4(acc[0], acc[1], acc[2], acc[3]);
        *(float4*)(dp + 4) = make_float4(acc[4], acc[5], acc[6], acc[7]);
    }
}

// Fallback: R9 direct f32 gather (no ws needed).
__global__ __launch_bounds__(256)
void flashkan_gather_f32(const float* __restrict__ x,
                         const float* __restrict__ w,
                         const float* __restrict__ t,
                         float* __restrict__ out) {
    __shared__ float t_sh[NKNOT];
    __shared__ float psum[4][O_DIM];
    const int tid  = threadIdx.x;
    const int b    = blockIdx.x;
    const int wave = tid >> 6;
    const int lane = tid & 63;
    const int l32  = lane & 31;
    if (tid < NKNOT) t_sh[tid] = t[tid];
    __syncthreads();
    float cf0, cf1, cf2, cf3, cf4; int cg;
    coef_eval(x[(size_t)b * I_DIM + wave * 32 + l32], t_sh,
              cf0, cf1, cf2, cf3, cf4, cg);
    const int i_base = wave * 32;
    float ax = 0.0f, ay = 0.0f;
    #pragma unroll 8
    for (int k = 0; k < 32; ++k) {
        const float c0 = rdlanef(cf0, k), c1 = rdlanef(cf1, k);
        const float c2 = rdlanef(cf2, k), c3 = rdlanef(cf3, k);
        const float c4 = rdlanef(cf4, k);
        const int   g0 = __builtin_amdgcn_readlane(cg, k);
        const int i = i_base + k;
        const float2* base = (const float2*)(w + (size_t)i * O_DIM) + lane;
        const size_t rs = (size_t)I_DIM * O_DIM / 2;
        const float2 v0 = base[(size_t)g0 * rs];
        const float2 v1 = base[(size_t)(g0 + 1) * rs];
        const float2 v2 = base[(size_t)(g0 + 2) * rs];
        const float2 v3 = base[(size_t)(g0 + 3) * rs];
        const float2 v4 = base[(size_t)(GK - 1) * rs];
        ax += c0 * v0.x + c1 * v1.x + c2 * v2.x + c3 * v3.x + c4 * v4.x;
        ay += c0 * v0.y + c1 * v1.y + c2 * v2.y + c3 * v3.y + c4 * v4.y;
    }
    psum[wave][lane * 2]     = ax;
    psum[wave][lane * 2 + 1] = ay;
    __syncthreads();
    if (tid < O_DIM) {
        out[(size_t)b * O_DIM + tid] =
            psum[0][tid] + psum[1][tid] + psum[2][tid] + psum[3][tid];
    }
}

extern "C" void kernel_launch(void* const* d_in, const int* in_sizes, int n_in,
                              void* d_out, int out_size, void* d_ws, size_t ws_size,
                              hipStream_t stream) {
    const float* x = (const float*)d_in[0];
    const float* w = (const float*)d_in[1];
    const float* t = (const float*)d_in[2];
    float* out = (float*)d_out;

    if (ws_size >= WS_MIN) {
        unsigned short* wbf = (unsigned short*)d_ws;
        wcvt<<<(int)(W_ELEMS / (8 * 128)), 256, 0, stream>>>(w, wbf);  // 1088
        flashkan_quad<<<B_TOTAL / 8, 512, 0, stream>>>(x, wbf, t, out);
    } else {
        flashkan_gather_f32<<<B_TOTAL, 256, 0, stream>>>(x, w, t, out);
    }
}